// Round 5
// baseline (1157.473 us; speedup 1.0000x reference)
//
#include <hip/hip_runtime.h>
#include <hip/hip_bf16.h>
#include <stdint.h>

typedef __bf16 bf16;
typedef __bf16 bf16x2 __attribute__((ext_vector_type(2)));
typedef __bf16 bf16x4 __attribute__((ext_vector_type(4)));
typedef __bf16 bf16x8 __attribute__((ext_vector_type(8)));
typedef float f32x4 __attribute__((ext_vector_type(4)));

#define AS1 __attribute__((address_space(1)))
#define AS3 __attribute__((address_space(3)))

static __device__ __forceinline__ float b2f(bf16 x) { return (float)x; }

static __device__ __forceinline__ void async_cp16(const bf16* g, bf16* l) {
    __builtin_amdgcn_global_load_lds((const AS1 void*)g, (AS3 void*)l, 16, 0, 0);
}

static __device__ __forceinline__ bf16x4 cvt4(f32x4 v) {
    bf16x4 r;
    r[0] = (bf16)v[0]; r[1] = (bf16)v[1]; r[2] = (bf16)v[2]; r[3] = (bf16)v[3];
    return r;
}

// ---------------------------------------------------------------------------
// fp32 -> bf16 bulk convert (grid-stride, float4)
__global__ __launch_bounds__(256) void cvt_kernel(
    const float* __restrict__ src, bf16* __restrict__ dst, int n4) {
    int i = blockIdx.x * 256 + threadIdx.x;
    const int stride = gridDim.x * 256;
    for (; i < n4; i += stride)
        ((bf16x4*)dst)[i] = cvt4(((const f32x4*)src)[i]);
}

// ---------------------------------------------------------------------------
// QKV epilogue scatter (shared by both GEMM variants):
// n = s*1024 + h*64 + d; m = b*1568 + pix. V stored transposed [g][d][ppix]
// with within-32 key permutation ppix = base32 | ((lk&15)<<1) | (lk>>4).
static __device__ __forceinline__ void qkv_epilogue(
    const f32x4 acc[4][4], const float* bias, bf16* Qb, bf16* Kb, bf16* Vt,
    int m0, int n0, int wm, int wn, int lm, int quad) {
    for (int nt = 0; nt < 4; nt++) {
        const int n_ = n0 + wn + nt * 16 + lm;
        const float bv = bias[n_];
        const int s = n_ >> 10, rem = n_ & 1023;
        const int h = rem >> 6, d = rem & 63;
        for (int mt = 0; mt < 4; mt++) {
            for (int r = 0; r < 4; r++) {
                const int m_ = m0 + wm + mt * 16 + quad * 4 + r;
                const int b = m_ / 1568;
                const int pix = m_ - b * 1568;
                const int g = b * 16 + h;
                const bf16 v = (bf16)(acc[mt][nt][r] + bv);
                if (s == 0)      Qb[((size_t)g * 1568 + pix) * 64 + d] = v;
                else if (s == 1) Kb[((size_t)g * 1568 + pix) * 64 + d] = v;
                else {
                    const int lk = pix & 31;
                    const int ppix = (pix & ~31) | ((lk & 15) << 1) | (lk >> 4);
                    Vt[((size_t)g * 64 + d) * 1568 + ppix] = v;
                }
            }
        }
    }
}

// ---------------------------------------------------------------------------
// Kernel 1a: QKV projection, bf16 inputs (pre-converted), m97 async staging.
__global__ __launch_bounds__(256) void qkv_gemm_bf16(
    const bf16* __restrict__ A, const bf16* __restrict__ W,
    const float* __restrict__ bias, bf16* __restrict__ Qb,
    bf16* __restrict__ Kb, bf16* __restrict__ Vt) {
    __shared__ bf16 As[128 * 32];
    __shared__ bf16 Bs[128 * 32];
    const int t = threadIdx.x;
    const int wid = t >> 6, lane = t & 63;
    const int m0 = blockIdx.x * 128, n0 = blockIdx.y * 128;
    const int wm = (wid & 1) * 64, wn = (wid >> 1) * 64;
    const int r_i = lane >> 2, c8 = (lane & 3) * 8;
    const int lm = lane & 15, quad = lane >> 4;

    f32x4 acc[4][4] = {};
    for (int k0 = 0; k0 < 1024; k0 += 32) {
        __syncthreads();
        for (int i = 0; i < 2; i++) {
            const int blk = wid * 2 + i;
            async_cp16(A + (size_t)(m0 + blk * 16 + r_i) * 1024 + k0 + c8, As + blk * 512);
            async_cp16(W + (size_t)(n0 + blk * 16 + r_i) * 1024 + k0 + c8, Bs + blk * 512);
        }
        __syncthreads();
        bf16x8 af[4], bfr[4];
        for (int x = 0; x < 4; x++) {
            af[x]  = *(const bf16x8*)&As[(wm + x * 16 + lm) * 32 + quad * 8];
            bfr[x] = *(const bf16x8*)&Bs[(wn + x * 16 + lm) * 32 + quad * 8];
        }
        for (int mt = 0; mt < 4; mt++)
            for (int nt = 0; nt < 4; nt++)
                acc[mt][nt] = __builtin_amdgcn_mfma_f32_16x16x32_bf16(af[mt], bfr[nt], acc[mt][nt], 0, 0, 0);
    }
    qkv_epilogue(acc, bias, Qb, Kb, Vt, m0, n0, wm, wn, lm, quad);
}

// Kernel 1b: fallback — fp32 inputs, convert at LDS-stage time (round-4 path).
__global__ __launch_bounds__(256) void qkv_gemm_f32(
    const float* __restrict__ A, const float* __restrict__ W,
    const float* __restrict__ bias, bf16* __restrict__ Qb,
    bf16* __restrict__ Kb, bf16* __restrict__ Vt) {
    __shared__ bf16 As[128 * 32];
    __shared__ bf16 Bs[128 * 32];
    const int t = threadIdx.x;
    const int wid = t >> 6, lane = t & 63;
    const int m0 = blockIdx.x * 128, n0 = blockIdx.y * 128;
    const int wm = (wid & 1) * 64, wn = (wid >> 1) * 64;
    const int lm = lane & 15, quad = lane >> 4;

    f32x4 acc[4][4] = {};
    for (int k0 = 0; k0 < 1024; k0 += 32) {
        __syncthreads();
        for (int i = 0; i < 4; i++) {
            const int idx = t + i * 256;
            const int row = idx >> 3, c4 = (idx & 7) * 4;
            const f32x4 av = *(const f32x4*)&A[(size_t)(m0 + row) * 1024 + k0 + c4];
            const f32x4 wv = *(const f32x4*)&W[(size_t)(n0 + row) * 1024 + k0 + c4];
            *(bf16x4*)&As[row * 32 + c4] = cvt4(av);
            *(bf16x4*)&Bs[row * 32 + c4] = cvt4(wv);
        }
        __syncthreads();
        bf16x8 af[4], bfr[4];
        for (int x = 0; x < 4; x++) {
            af[x]  = *(const bf16x8*)&As[(wm + x * 16 + lm) * 32 + quad * 8];
            bfr[x] = *(const bf16x8*)&Bs[(wn + x * 16 + lm) * 32 + quad * 8];
        }
        for (int mt = 0; mt < 4; mt++)
            for (int nt = 0; nt < 4; nt++)
                acc[mt][nt] = __builtin_amdgcn_mfma_f32_16x16x32_bf16(af[mt], bfr[nt], acc[mt][nt], 0, 0, 0);
    }
    qkv_epilogue(acc, bias, Qb, Kb, Vt, m0, n0, wm, wn, lm, quad);
}

// ---------------------------------------------------------------------------
// Kernel 2: flash attention, fixed-shift softmax, register-prefetched K/V
// tiles (global->VGPR loads cross the barrier without vmcnt(0) drain),
// XCD-swizzled 1-D grid: xcd = blk&7 owns heads [8*xcd, 8*xcd+8) so each
// XCD's L2 streams only 3.2 MB of K/V.
__global__ __launch_bounds__(256) void flash_attn(
    const bf16* __restrict__ Qb, const bf16* __restrict__ Kb,
    const bf16* __restrict__ Vt, const float* __restrict__ rph,
    const float* __restrict__ rpw, bf16* __restrict__ AO) {
    const int x = blockIdx.x;
    const int xcd = x & 7, j = x >> 3;          // j in 0..199
    const int g = xcd * 8 + j / 25;
    const int qblk = j - (j / 25) * 25;
    const int q0 = qblk * 64;
    // 40448 B -> 4 blocks/CU. Ps aliases Qs (Qs dead after prologue).
    __shared__ __align__(16) char smem[40448];
    bf16*  Qs     = (bf16*)smem;            // [64][72] prologue only
    bf16*  Ps     = (bf16*)smem;            // [4][16][40] aliases Qs
    float* relh_s = (float*)(smem + 9216);  // [64][56]
    float* relw_s = (float*)(smem + 23552); // [64][28]
    bf16*  Ks     = (bf16*)(smem + 30720);  // [32][72]
    bf16*  Vts    = (bf16*)(smem + 35328);  // [64][40] (cols = permuted pos)

    const int t = threadIdx.x, wid = t >> 6, lane = t & 63;
    const int lm = lane & 15, quad = lane >> 4;

    // stage Q tile [64][64] -> LDS (rows clamped for the q tail)
    for (int c = t; c < 512; c += 256) {
        const int row = c >> 3, col = (c & 7) * 8;
        const int qg = min(q0 + row, 1567);
        *(bf16x8*)&Qs[row * 72 + col] =
            *(const bf16x8*)&Qb[((size_t)g * 1568 + qg) * 64 + col];
    }
    __syncthreads();

    // rel-pos biases: relh_s[ql][hk] = Q[ql].rph[hq-hk+55]; relw_s similar.
    for (int e = t; e < 64 * 84; e += 256) {
        const int ql = e / 84, jj = e - ql * 84;
        const int qg = min(q0 + ql, 1567);
        const int hq = qg / 28, wq = qg - hq * 28;
        const float* rp;
        float* dst;
        if (jj < 56) { rp = rph + (hq - jj + 55) * 64;      dst = &relh_s[ql * 56 + jj]; }
        else { const int wk = jj - 56;
               rp = rpw + (wq - wk + 27) * 64;              dst = &relw_s[ql * 28 + wk]; }
        float s = 0.f;
#pragma unroll
        for (int c = 0; c < 8; c++) {
            const bf16x8 qv = *(const bf16x8*)&Qs[ql * 72 + c * 8];
            const f32x4 r0 = *(const f32x4*)&rp[c * 8];
            const f32x4 r1 = *(const f32x4*)&rp[c * 8 + 4];
#pragma unroll
            for (int k = 0; k < 4; k++) s += b2f(qv[k]) * r0[k];
#pragma unroll
            for (int k = 0; k < 4; k++) s += b2f(qv[k + 4]) * r1[k];
        }
        *dst = s;
    }

    // Q MFMA A-fragments from LDS (before first loop barrier — Qs dies here)
    const int qrow_l = wid * 16 + lm;
    const bf16x8 qf0 = *(const bf16x8*)&Qs[qrow_l * 72 + quad * 8];
    const bf16x8 qf1 = *(const bf16x8*)&Qs[qrow_l * 72 + 32 + quad * 8];

    f32x4 o[4] = {};
    float l_lane[4] = {0.f, 0.f, 0.f, 0.f};
    const float scale = 0.125f;
    const float SHIFT = 10.0f;

    const int ks_k = t >> 3, ks_d = (t & 7) * 8;   // K staging coords
    const int vs_d = t >> 2, vs_k = (t & 3) * 8;   // Vt staging coords
    bf16* Pw = &Ps[wid * 640];
    const int qbase_l = wid * 16 + quad * 4;

    // register prefetch of tile 0
    const size_t kgbase = ((size_t)g * 1568 + ks_k) * 64 + ks_d;
    const size_t vgbase = ((size_t)g * 64 + vs_d) * 1568 + vs_k;
    bf16x8 kreg = *(const bf16x8*)&Kb[kgbase];
    bf16x8 vreg = *(const bf16x8*)&Vt[vgbase];

    for (int kt = 0; kt < 49; kt++) {
        const int kb = kt * 32;
        __syncthreads();                           // prev tile's readers done
        *(bf16x8*)&Ks[ks_k * 72 + ks_d] = kreg;
        *(bf16x8*)&Vts[vs_d * 40 + vs_k] = vreg;
        if (kt + 1 < 49) {                         // issue next tile's loads;
            kreg = *(const bf16x8*)&Kb[kgbase + (size_t)(kt + 1) * 2048];
            vreg = *(const bf16x8*)&Vt[vgbase + (kt + 1) * 32];
        }
        __syncthreads();

        // S = Q K^T  (two 16-key fragments; key = kb + lm / kb + 16 + lm)
        f32x4 s0 = {}, s1 = {};
        {
            const bf16x8 ka0 = *(const bf16x8*)&Ks[lm * 72 + quad * 8];
            const bf16x8 ka1 = *(const bf16x8*)&Ks[lm * 72 + 32 + quad * 8];
            s0 = __builtin_amdgcn_mfma_f32_16x16x32_bf16(qf0, ka0, s0, 0, 0, 0);
            s0 = __builtin_amdgcn_mfma_f32_16x16x32_bf16(qf1, ka1, s0, 0, 0, 0);
            const bf16x8 kb0 = *(const bf16x8*)&Ks[(16 + lm) * 72 + quad * 8];
            const bf16x8 kb1 = *(const bf16x8*)&Ks[(16 + lm) * 72 + 32 + quad * 8];
            s1 = __builtin_amdgcn_mfma_f32_16x16x32_bf16(qf0, kb0, s1, 0, 0, 0);
            s1 = __builtin_amdgcn_mfma_f32_16x16x32_bf16(qf1, kb1, s1, 0, 0, 0);
        }

        // bias + fixed-shift exp; P packed as bf16x2 at permuted positions
        const int key0 = kb + lm, key1 = key0 + 16;
        const int hk0 = key0 / 28, wk0 = key0 - hk0 * 28;
        const int hk1 = key1 / 28, wk1 = key1 - hk1 * 28;
        for (int r = 0; r < 4; r++) {
            const int ql = qbase_l + r;
            const float p0 = __expf(s0[r] * scale + relh_s[ql * 56 + hk0]
                                    + relw_s[ql * 28 + wk0] - SHIFT);
            const float p1 = __expf(s1[r] * scale + relh_s[ql * 56 + hk1]
                                    + relw_s[ql * 28 + wk1] - SHIFT);
            l_lane[r] += p0 + p1;
            bf16x2 pp; pp[0] = (bf16)p0; pp[1] = (bf16)p1;
            *(bf16x2*)&Pw[(quad * 4 + r) * 40 + lm * 2] = pp;  // pos 2lm, 2lm+1
        }
        __asm__ volatile("s_waitcnt lgkmcnt(0)" ::: "memory");
        const bf16x8 pf = *(const bf16x8*)&Pw[lm * 40 + quad * 8];
        for (int dt = 0; dt < 4; dt++) {
            const bf16x8 vf = *(const bf16x8*)&Vts[(dt * 16 + lm) * 40 + quad * 8];
            o[dt] = __builtin_amdgcn_mfma_f32_16x16x32_bf16(pf, vf, o[dt], 0, 0, 0);
        }
    }

    // single l reduction (16 lanes per row group), then epilogue
    const int qrow0 = q0 + wid * 16 + quad * 4;
    if (q0 + wid * 16 < 1568) {
        const int bo = g >> 4, h = g & 15;
        for (int r = 0; r < 4; r++) {
            float ll = l_lane[r];
            for (int off = 1; off < 16; off <<= 1) ll += __shfl_xor(ll, off, 64);
            const float inv = 1.0f / ll;
            const size_t base = ((size_t)bo * 1568 + qrow0 + r) * 1024 + h * 64;
            for (int dt = 0; dt < 4; dt++)
                AO[base + dt * 16 + lm] = (bf16)(o[dt][r] * inv);
        }
    }
}

// ---------------------------------------------------------------------------
// Kernel 3a: output projection, both operands bf16 (W pre-converted).
__global__ __launch_bounds__(256) void proj_gemm_bf16(
    const bf16* __restrict__ A, const bf16* __restrict__ W,
    const float* __restrict__ bias, float* __restrict__ out) {
    __shared__ bf16 As[128 * 32];
    __shared__ bf16 Bs[128 * 32];
    const int t = threadIdx.x;
    const int wid = t >> 6, lane = t & 63;
    const int m0 = blockIdx.x * 128, n0 = blockIdx.y * 128;
    const int wm = (wid & 1) * 64, wn = (wid >> 1) * 64;
    const int r_i = lane >> 2, c8 = (lane & 3) * 8;
    const int lm = lane & 15, quad = lane >> 4;

    f32x4 acc[4][4] = {};
    for (int k0 = 0; k0 < 1024; k0 += 32) {
        __syncthreads();
        for (int i = 0; i < 2; i++) {
            const int blk = wid * 2 + i;
            async_cp16(A + (size_t)(m0 + blk * 16 + r_i) * 1024 + k0 + c8, As + blk * 512);
            async_cp16(W + (size_t)(n0 + blk * 16 + r_i) * 1024 + k0 + c8, Bs + blk * 512);
        }
        __syncthreads();
        bf16x8 af[4], bfr[4];
        for (int x = 0; x < 4; x++) {
            af[x]  = *(const bf16x8*)&As[(wm + x * 16 + lm) * 32 + quad * 8];
            bfr[x] = *(const bf16x8*)&Bs[(wn + x * 16 + lm) * 32 + quad * 8];
        }
        for (int mt = 0; mt < 4; mt++)
            for (int nt = 0; nt < 4; nt++)
                acc[mt][nt] = __builtin_amdgcn_mfma_f32_16x16x32_bf16(af[mt], bfr[nt], acc[mt][nt], 0, 0, 0);
    }
    for (int nt = 0; nt < 4; nt++) {
        const int n_ = n0 + wn + nt * 16 + lm;
        const float bv = bias[n_];
        for (int mt = 0; mt < 4; mt++)
            for (int r = 0; r < 4; r++) {
                const int m_ = m0 + wm + mt * 16 + quad * 4 + r;
                out[(size_t)m_ * 1024 + n_] = acc[mt][nt][r] + bv;
            }
    }
}

// Kernel 3b: fallback — W fp32, converted at stage time (round-4 path).
__global__ __launch_bounds__(256) void proj_gemm_f32(
    const bf16* __restrict__ A, const float* __restrict__ W,
    const float* __restrict__ bias, float* __restrict__ out) {
    __shared__ bf16 As[128 * 32];
    __shared__ bf16 Bs[128 * 32];
    const int t = threadIdx.x;
    const int wid = t >> 6, lane = t & 63;
    const int m0 = blockIdx.x * 128, n0 = blockIdx.y * 128;
    const int wm = (wid & 1) * 64, wn = (wid >> 1) * 64;
    const int r_i = lane >> 2, c8 = (lane & 3) * 8;
    const int lm = lane & 15, quad = lane >> 4;

    f32x4 acc[4][4] = {};
    for (int k0 = 0; k0 < 1024; k0 += 32) {
        __syncthreads();
        for (int i = 0; i < 2; i++) {
            const int blk = wid * 2 + i;
            async_cp16(A + (size_t)(m0 + blk * 16 + r_i) * 1024 + k0 + c8, As + blk * 512);
        }
        for (int i = 0; i < 4; i++) {
            const int idx = t + i * 256;
            const int row = idx >> 3, c4 = (idx & 7) * 4;
            const f32x4 wv = *(const f32x4*)&W[(size_t)(n0 + row) * 1024 + k0 + c4];
            *(bf16x4*)&Bs[row * 32 + c4] = cvt4(wv);
        }
        __syncthreads();
        bf16x8 af[4], bfr[4];
        for (int x = 0; x < 4; x++) {
            af[x]  = *(const bf16x8*)&As[(wm + x * 16 + lm) * 32 + quad * 8];
            bfr[x] = *(const bf16x8*)&Bs[(wn + x * 16 + lm) * 32 + quad * 8];
        }
        for (int mt = 0; mt < 4; mt++)
            for (int nt = 0; nt < 4; nt++)
                acc[mt][nt] = __builtin_amdgcn_mfma_f32_16x16x32_bf16(af[mt], bfr[nt], acc[mt][nt], 0, 0, 0);
    }
    for (int nt = 0; nt < 4; nt++) {
        const int n_ = n0 + wn + nt * 16 + lm;
        const float bv = bias[n_];
        for (int mt = 0; mt < 4; mt++)
            for (int r = 0; r < 4; r++) {
                const int m_ = m0 + wm + mt * 16 + quad * 4 + r;
                out[(size_t)m_ * 1024 + n_] = acc[mt][nt][r] + bv;
            }
    }
}

// ---------------------------------------------------------------------------
extern "C" void kernel_launch(void* const* d_in, const int* in_sizes, int n_in,
                              void* d_out, int out_size, void* d_ws, size_t ws_size,
                              hipStream_t stream) {
    const float* hs     = (const float*)d_in[0];
    const float* qkv_w  = (const float*)d_in[1];
    const float* qkv_b  = (const float*)d_in[2];
    const float* proj_w = (const float*)d_in[3];
    const float* proj_b = (const float*)d_in[4];
    const float* rph    = (const float*)d_in[5];
    const float* rpw    = (const float*)d_in[6];
    float* out = (float*)d_out;

    const size_t GQ = (size_t)64 * 1568 * 64;  // elems per Q/K/V
    const size_t N_HS = (size_t)6272 * 1024;   // 6,422,528
    const size_t N_QW = (size_t)3072 * 1024;   // 3,145,728
    const size_t N_PW = (size_t)1024 * 1024;   // 1,048,576
    bf16* Qb = (bf16*)d_ws;                    // [g][pix][64]
    bf16* Kb = Qb + GQ;                        // [g][pix][64]
    bf16* Vt = Kb + GQ;                        // [g][d][ppix] (permuted keys)
    bf16* AO = Vt + GQ;                        // [6272][1024]
    bf16* hs_bf    = AO + GQ;
    bf16* qkvw_bf  = hs_bf + N_HS;
    bf16* projw_bf = qkvw_bf + N_QW;
    const size_t need = (4 * GQ + N_HS + N_QW + N_PW) * sizeof(bf16); // 72.6 MB

    if (ws_size >= need) {
        cvt_kernel<<<512, 256, 0, stream>>>(hs, hs_bf, (int)(N_HS / 4));
        cvt_kernel<<<512, 256, 0, stream>>>(qkv_w, qkvw_bf, (int)(N_QW / 4));
        cvt_kernel<<<256, 256, 0, stream>>>(proj_w, projw_bf, (int)(N_PW / 4));
        qkv_gemm_bf16<<<dim3(49, 24), 256, 0, stream>>>(hs_bf, qkvw_bf, qkv_b, Qb, Kb, Vt);
        flash_attn<<<1600, 256, 0, stream>>>(Qb, Kb, Vt, rph, rpw, AO);
        proj_gemm_bf16<<<dim3(49, 8), 256, 0, stream>>>(AO, projw_bf, proj_b, out);
    } else {
        qkv_gemm_f32<<<dim3(49, 24), 256, 0, stream>>>(hs, qkv_w, qkv_b, Qb, Kb, Vt);
        flash_attn<<<1600, 256, 0, stream>>>(Qb, Kb, Vt, rph, rpw, AO);
        proj_gemm_f32<<<dim3(49, 8), 256, 0, stream>>>(AO, proj_w, proj_b, out);
    }
}

// Round 6
// 567.979 us; speedup vs baseline: 2.0379x; 2.0379x over previous
//
#include <hip/hip_runtime.h>
#include <hip/hip_bf16.h>
#include <stdint.h>

typedef __bf16 bf16;
typedef __bf16 bf16x2 __attribute__((ext_vector_type(2)));
typedef __bf16 bf16x4 __attribute__((ext_vector_type(4)));
typedef __bf16 bf16x8 __attribute__((ext_vector_type(8)));
typedef float f32x4 __attribute__((ext_vector_type(4)));

#define AS1 __attribute__((address_space(1)))
#define AS3 __attribute__((address_space(3)))

static __device__ __forceinline__ float b2f(bf16 x) { return (float)x; }

static __device__ __forceinline__ void async_cp16(const bf16* g, bf16* l) {
    __builtin_amdgcn_global_load_lds((const AS1 void*)g, (AS3 void*)l, 16, 0, 0);
}

static __device__ __forceinline__ bf16x4 cvt4(f32x4 v) {
    bf16x4 r;
    r[0] = (bf16)v[0]; r[1] = (bf16)v[1]; r[2] = (bf16)v[2]; r[3] = (bf16)v[3];
    return r;
}

// ---------------------------------------------------------------------------
// fp32 -> bf16 bulk convert (grid-stride, float4)
__global__ __launch_bounds__(256) void cvt_kernel(
    const float* __restrict__ src, bf16* __restrict__ dst, int n4) {
    int i = blockIdx.x * 256 + threadIdx.x;
    const int stride = gridDim.x * 256;
    for (; i < n4; i += stride)
        ((bf16x4*)dst)[i] = cvt4(((const f32x4*)src)[i]);
}

// NOTE: epilogue is INLINED in both qkv kernels. Round 5 passed acc[4][4]
// into a helper; array-decay defeated SROA -> acc lived in scratch -> every
// MFMA accumulate became a global-memory RMW (VGPR_Count 84, WRITE_SIZE
// 2.18 GB, 700 us). Do not refactor accumulators through pointers.

#define QKV_EPILOGUE()                                                        \
    for (int nt = 0; nt < 4; nt++) {                                          \
        const int n_ = n0 + wn + nt * 16 + lm;                                \
        const float bv = bias[n_];                                            \
        const int s = n_ >> 10, rem = n_ & 1023;                              \
        const int h = rem >> 6, d = rem & 63;                                 \
        for (int mt = 0; mt < 4; mt++) {                                      \
            for (int r = 0; r < 4; r++) {                                     \
                const int m_ = m0 + wm + mt * 16 + quad * 4 + r;              \
                const int b = m_ / 1568;                                      \
                const int pix = m_ - b * 1568;                                \
                const int g = b * 16 + h;                                     \
                const bf16 v = (bf16)(acc[mt][nt][r] + bv);                   \
                if (s == 0)      Qb[((size_t)g * 1568 + pix) * 64 + d] = v;   \
                else if (s == 1) Kb[((size_t)g * 1568 + pix) * 64 + d] = v;   \
                else {                                                        \
                    const int lk = pix & 31;                                  \
                    const int ppix = (pix & ~31) | ((lk & 15) << 1) | (lk >> 4); \
                    Vt[((size_t)g * 64 + d) * 1568 + ppix] = v;               \
                }                                                             \
            }                                                                 \
        }                                                                     \
    }

// ---------------------------------------------------------------------------
// Kernel 1a: QKV projection, bf16 inputs (pre-converted), m97 async staging.
// Q,K -> [g][pix][64]; V -> [g][d][ppix], ppix = within-32 key permutation
// matching flash's packed-P order.
__global__ __launch_bounds__(256) void qkv_gemm_bf16(
    const bf16* __restrict__ A, const bf16* __restrict__ W,
    const float* __restrict__ bias, bf16* __restrict__ Qb,
    bf16* __restrict__ Kb, bf16* __restrict__ Vt) {
    __shared__ bf16 As[128 * 32];
    __shared__ bf16 Bs[128 * 32];
    const int t = threadIdx.x;
    const int wid = t >> 6, lane = t & 63;
    const int m0 = blockIdx.x * 128, n0 = blockIdx.y * 128;
    const int wm = (wid & 1) * 64, wn = (wid >> 1) * 64;
    const int r_i = lane >> 2, c8 = (lane & 3) * 8;
    const int lm = lane & 15, quad = lane >> 4;

    f32x4 acc[4][4] = {};
    for (int k0 = 0; k0 < 1024; k0 += 32) {
        __syncthreads();
        for (int i = 0; i < 2; i++) {
            const int blk = wid * 2 + i;
            async_cp16(A + (size_t)(m0 + blk * 16 + r_i) * 1024 + k0 + c8, As + blk * 512);
            async_cp16(W + (size_t)(n0 + blk * 16 + r_i) * 1024 + k0 + c8, Bs + blk * 512);
        }
        __syncthreads();
        bf16x8 af[4], bfr[4];
        for (int x = 0; x < 4; x++) {
            af[x]  = *(const bf16x8*)&As[(wm + x * 16 + lm) * 32 + quad * 8];
            bfr[x] = *(const bf16x8*)&Bs[(wn + x * 16 + lm) * 32 + quad * 8];
        }
        for (int mt = 0; mt < 4; mt++)
            for (int nt = 0; nt < 4; nt++)
                acc[mt][nt] = __builtin_amdgcn_mfma_f32_16x16x32_bf16(af[mt], bfr[nt], acc[mt][nt], 0, 0, 0);
    }
    QKV_EPILOGUE()
}

// Kernel 1b: fallback — fp32 inputs, convert at LDS-stage time.
__global__ __launch_bounds__(256) void qkv_gemm_f32(
    const float* __restrict__ A, const float* __restrict__ W,
    const float* __restrict__ bias, bf16* __restrict__ Qb,
    bf16* __restrict__ Kb, bf16* __restrict__ Vt) {
    __shared__ bf16 As[128 * 32];
    __shared__ bf16 Bs[128 * 32];
    const int t = threadIdx.x;
    const int wid = t >> 6, lane = t & 63;
    const int m0 = blockIdx.x * 128, n0 = blockIdx.y * 128;
    const int wm = (wid & 1) * 64, wn = (wid >> 1) * 64;
    const int lm = lane & 15, quad = lane >> 4;

    f32x4 acc[4][4] = {};
    for (int k0 = 0; k0 < 1024; k0 += 32) {
        __syncthreads();
        for (int i = 0; i < 4; i++) {
            const int idx = t + i * 256;
            const int row = idx >> 3, c4 = (idx & 7) * 4;
            const f32x4 av = *(const f32x4*)&A[(size_t)(m0 + row) * 1024 + k0 + c4];
            const f32x4 wv = *(const f32x4*)&W[(size_t)(n0 + row) * 1024 + k0 + c4];
            *(bf16x4*)&As[row * 32 + c4] = cvt4(av);
            *(bf16x4*)&Bs[row * 32 + c4] = cvt4(wv);
        }
        __syncthreads();
        bf16x8 af[4], bfr[4];
        for (int x = 0; x < 4; x++) {
            af[x]  = *(const bf16x8*)&As[(wm + x * 16 + lm) * 32 + quad * 8];
            bfr[x] = *(const bf16x8*)&Bs[(wn + x * 16 + lm) * 32 + quad * 8];
        }
        for (int mt = 0; mt < 4; mt++)
            for (int nt = 0; nt < 4; nt++)
                acc[mt][nt] = __builtin_amdgcn_mfma_f32_16x16x32_bf16(af[mt], bfr[nt], acc[mt][nt], 0, 0, 0);
    }
    QKV_EPILOGUE()
}

// ---------------------------------------------------------------------------
// Kernel 2: flash attention, fixed-shift softmax, register-prefetched K/V
// tiles, XCD-swizzled 1-D grid (xcd = blk&7 owns heads [8*xcd, 8*xcd+8)).
__global__ __launch_bounds__(256) void flash_attn(
    const bf16* __restrict__ Qb, const bf16* __restrict__ Kb,
    const bf16* __restrict__ Vt, const float* __restrict__ rph,
    const float* __restrict__ rpw, bf16* __restrict__ AO) {
    const int x = blockIdx.x;
    const int xcd = x & 7, j = x >> 3;          // j in 0..199
    const int g = xcd * 8 + j / 25;
    const int qblk = j - (j / 25) * 25;
    const int q0 = qblk * 64;
    // 40448 B -> 4 blocks/CU. Ps aliases Qs (Qs dead after prologue).
    __shared__ __align__(16) char smem[40448];
    bf16*  Qs     = (bf16*)smem;            // [64][72] prologue only
    bf16*  Ps     = (bf16*)smem;            // [4][16][40] aliases Qs
    float* relh_s = (float*)(smem + 9216);  // [64][56]
    float* relw_s = (float*)(smem + 23552); // [64][28]
    bf16*  Ks     = (bf16*)(smem + 30720);  // [32][72]
    bf16*  Vts    = (bf16*)(smem + 35328);  // [64][40] (cols = permuted pos)

    const int t = threadIdx.x, wid = t >> 6, lane = t & 63;
    const int lm = lane & 15, quad = lane >> 4;

    // stage Q tile [64][64] -> LDS (rows clamped for the q tail)
    for (int c = t; c < 512; c += 256) {
        const int row = c >> 3, col = (c & 7) * 8;
        const int qg = min(q0 + row, 1567);
        *(bf16x8*)&Qs[row * 72 + col] =
            *(const bf16x8*)&Qb[((size_t)g * 1568 + qg) * 64 + col];
    }
    __syncthreads();

    // rel-pos biases: relh_s[ql][hk] = Q[ql].rph[hq-hk+55]; relw_s similar.
    for (int e = t; e < 64 * 84; e += 256) {
        const int ql = e / 84, jj = e - ql * 84;
        const int qg = min(q0 + ql, 1567);
        const int hq = qg / 28, wq = qg - hq * 28;
        const float* rp;
        float* dst;
        if (jj < 56) { rp = rph + (hq - jj + 55) * 64;      dst = &relh_s[ql * 56 + jj]; }
        else { const int wk = jj - 56;
               rp = rpw + (wq - wk + 27) * 64;              dst = &relw_s[ql * 28 + wk]; }
        float s = 0.f;
#pragma unroll
        for (int c = 0; c < 8; c++) {
            const bf16x8 qv = *(const bf16x8*)&Qs[ql * 72 + c * 8];
            const f32x4 r0 = *(const f32x4*)&rp[c * 8];
            const f32x4 r1 = *(const f32x4*)&rp[c * 8 + 4];
#pragma unroll
            for (int k = 0; k < 4; k++) s += b2f(qv[k]) * r0[k];
#pragma unroll
            for (int k = 0; k < 4; k++) s += b2f(qv[k + 4]) * r1[k];
        }
        *dst = s;
    }

    // Q MFMA A-fragments from LDS (before first loop barrier — Qs dies here)
    const int qrow_l = wid * 16 + lm;
    const bf16x8 qf0 = *(const bf16x8*)&Qs[qrow_l * 72 + quad * 8];
    const bf16x8 qf1 = *(const bf16x8*)&Qs[qrow_l * 72 + 32 + quad * 8];

    f32x4 o[4] = {};
    float l_lane[4] = {0.f, 0.f, 0.f, 0.f};
    const float scale = 0.125f;
    const float SHIFT = 10.0f;

    const int ks_k = t >> 3, ks_d = (t & 7) * 8;   // K staging coords
    const int vs_d = t >> 2, vs_k = (t & 3) * 8;   // Vt staging coords
    bf16* Pw = &Ps[wid * 640];
    const int qbase_l = wid * 16 + quad * 4;

    // register prefetch of tile 0
    const size_t kgbase = ((size_t)g * 1568 + ks_k) * 64 + ks_d;
    const size_t vgbase = ((size_t)g * 64 + vs_d) * 1568 + vs_k;
    bf16x8 kreg = *(const bf16x8*)&Kb[kgbase];
    bf16x8 vreg = *(const bf16x8*)&Vt[vgbase];

    for (int kt = 0; kt < 49; kt++) {
        const int kb = kt * 32;
        __syncthreads();                           // prev tile's readers done
        *(bf16x8*)&Ks[ks_k * 72 + ks_d] = kreg;
        *(bf16x8*)&Vts[vs_d * 40 + vs_k] = vreg;
        if (kt + 1 < 49) {                         // next tile's loads retire
            kreg = *(const bf16x8*)&Kb[kgbase + (size_t)(kt + 1) * 2048];
            vreg = *(const bf16x8*)&Vt[vgbase + (kt + 1) * 32];
        }
        __syncthreads();

        // S = Q K^T  (two 16-key fragments; key = kb + lm / kb + 16 + lm)
        f32x4 s0 = {}, s1 = {};
        {
            const bf16x8 ka0 = *(const bf16x8*)&Ks[lm * 72 + quad * 8];
            const bf16x8 ka1 = *(const bf16x8*)&Ks[lm * 72 + 32 + quad * 8];
            s0 = __builtin_amdgcn_mfma_f32_16x16x32_bf16(qf0, ka0, s0, 0, 0, 0);
            s0 = __builtin_amdgcn_mfma_f32_16x16x32_bf16(qf1, ka1, s0, 0, 0, 0);
            const bf16x8 kb0 = *(const bf16x8*)&Ks[(16 + lm) * 72 + quad * 8];
            const bf16x8 kb1 = *(const bf16x8*)&Ks[(16 + lm) * 72 + 32 + quad * 8];
            s1 = __builtin_amdgcn_mfma_f32_16x16x32_bf16(qf0, kb0, s1, 0, 0, 0);
            s1 = __builtin_amdgcn_mfma_f32_16x16x32_bf16(qf1, kb1, s1, 0, 0, 0);
        }

        // bias + fixed-shift exp; P packed as bf16x2 at permuted positions
        const int key0 = kb + lm, key1 = key0 + 16;
        const int hk0 = key0 / 28, wk0 = key0 - hk0 * 28;
        const int hk1 = key1 / 28, wk1 = key1 - hk1 * 28;
        for (int r = 0; r < 4; r++) {
            const int ql = qbase_l + r;
            const float p0 = __expf(s0[r] * scale + relh_s[ql * 56 + hk0]
                                    + relw_s[ql * 28 + wk0] - SHIFT);
            const float p1 = __expf(s1[r] * scale + relh_s[ql * 56 + hk1]
                                    + relw_s[ql * 28 + wk1] - SHIFT);
            l_lane[r] += p0 + p1;
            bf16x2 pp; pp[0] = (bf16)p0; pp[1] = (bf16)p1;
            *(bf16x2*)&Pw[(quad * 4 + r) * 40 + lm * 2] = pp;  // pos 2lm, 2lm+1
        }
        __asm__ volatile("s_waitcnt lgkmcnt(0)" ::: "memory");
        const bf16x8 pf = *(const bf16x8*)&Pw[lm * 40 + quad * 8];
        for (int dt = 0; dt < 4; dt++) {
            const bf16x8 vf = *(const bf16x8*)&Vts[(dt * 16 + lm) * 40 + quad * 8];
            o[dt] = __builtin_amdgcn_mfma_f32_16x16x32_bf16(pf, vf, o[dt], 0, 0, 0);
        }
    }

    // single l reduction (16 lanes per row group), then epilogue
    const int qrow0 = q0 + wid * 16 + quad * 4;
    if (q0 + wid * 16 < 1568) {
        const int bo = g >> 4, h = g & 15;
        for (int r = 0; r < 4; r++) {
            float ll = l_lane[r];
            for (int off = 1; off < 16; off <<= 1) ll += __shfl_xor(ll, off, 64);
            const float inv = 1.0f / ll;
            const size_t base = ((size_t)bo * 1568 + qrow0 + r) * 1024 + h * 64;
            for (int dt = 0; dt < 4; dt++)
                AO[base + dt * 16 + lm] = (bf16)(o[dt][r] * inv);
        }
    }
}

// ---------------------------------------------------------------------------
// Kernel 3a: output projection, both operands bf16 (W pre-converted).
__global__ __launch_bounds__(256) void proj_gemm_bf16(
    const bf16* __restrict__ A, const bf16* __restrict__ W,
    const float* __restrict__ bias, float* __restrict__ out) {
    __shared__ bf16 As[128 * 32];
    __shared__ bf16 Bs[128 * 32];
    const int t = threadIdx.x;
    const int wid = t >> 6, lane = t & 63;
    const int m0 = blockIdx.x * 128, n0 = blockIdx.y * 128;
    const int wm = (wid & 1) * 64, wn = (wid >> 1) * 64;
    const int r_i = lane >> 2, c8 = (lane & 3) * 8;
    const int lm = lane & 15, quad = lane >> 4;

    f32x4 acc[4][4] = {};
    for (int k0 = 0; k0 < 1024; k0 += 32) {
        __syncthreads();
        for (int i = 0; i < 2; i++) {
            const int blk = wid * 2 + i;
            async_cp16(A + (size_t)(m0 + blk * 16 + r_i) * 1024 + k0 + c8, As + blk * 512);
            async_cp16(W + (size_t)(n0 + blk * 16 + r_i) * 1024 + k0 + c8, Bs + blk * 512);
        }
        __syncthreads();
        bf16x8 af[4], bfr[4];
        for (int x = 0; x < 4; x++) {
            af[x]  = *(const bf16x8*)&As[(wm + x * 16 + lm) * 32 + quad * 8];
            bfr[x] = *(const bf16x8*)&Bs[(wn + x * 16 + lm) * 32 + quad * 8];
        }
        for (int mt = 0; mt < 4; mt++)
            for (int nt = 0; nt < 4; nt++)
                acc[mt][nt] = __builtin_amdgcn_mfma_f32_16x16x32_bf16(af[mt], bfr[nt], acc[mt][nt], 0, 0, 0);
    }
    for (int nt = 0; nt < 4; nt++) {
        const int n_ = n0 + wn + nt * 16 + lm;
        const float bv = bias[n_];
        for (int mt = 0; mt < 4; mt++)
            for (int r = 0; r < 4; r++) {
                const int m_ = m0 + wm + mt * 16 + quad * 4 + r;
                out[(size_t)m_ * 1024 + n_] = acc[mt][nt][r] + bv;
            }
    }
}

// Kernel 3b: fallback — W fp32, converted at stage time.
__global__ __launch_bounds__(256) void proj_gemm_f32(
    const bf16* __restrict__ A, const float* __restrict__ W,
    const float* __restrict__ bias, float* __restrict__ out) {
    __shared__ bf16 As[128 * 32];
    __shared__ bf16 Bs[128 * 32];
    const int t = threadIdx.x;
    const int wid = t >> 6, lane = t & 63;
    const int m0 = blockIdx.x * 128, n0 = blockIdx.y * 128;
    const int wm = (wid & 1) * 64, wn = (wid >> 1) * 64;
    const int r_i = lane >> 2, c8 = (lane & 3) * 8;
    const int lm = lane & 15, quad = lane >> 4;

    f32x4 acc[4][4] = {};
    for (int k0 = 0; k0 < 1024; k0 += 32) {
        __syncthreads();
        for (int i = 0; i < 2; i++) {
            const int blk = wid * 2 + i;
            async_cp16(A + (size_t)(m0 + blk * 16 + r_i) * 1024 + k0 + c8, As + blk * 512);
        }
        for (int i = 0; i < 4; i++) {
            const int idx = t + i * 256;
            const int row = idx >> 3, c4 = (idx & 7) * 4;
            const f32x4 wv = *(const f32x4*)&W[(size_t)(n0 + row) * 1024 + k0 + c4];
            *(bf16x4*)&Bs[row * 32 + c4] = cvt4(wv);
        }
        __syncthreads();
        bf16x8 af[4], bfr[4];
        for (int x = 0; x < 4; x++) {
            af[x]  = *(const bf16x8*)&As[(wm + x * 16 + lm) * 32 + quad * 8];
            bfr[x] = *(const bf16x8*)&Bs[(wn + x * 16 + lm) * 32 + quad * 8];
        }
        for (int mt = 0; mt < 4; mt++)
            for (int nt = 0; nt < 4; nt++)
                acc[mt][nt] = __builtin_amdgcn_mfma_f32_16x16x32_bf16(af[mt], bfr[nt], acc[mt][nt], 0, 0, 0);
    }
    for (int nt = 0; nt < 4; nt++) {
        const int n_ = n0 + wn + nt * 16 + lm;
        const float bv = bias[n_];
        for (int mt = 0; mt < 4; mt++)
            for (int r = 0; r < 4; r++) {
                const int m_ = m0 + wm + mt * 16 + quad * 4 + r;
                out[(size_t)m_ * 1024 + n_] = acc[mt][nt][r] + bv;
            }
    }
}

// ---------------------------------------------------------------------------
extern "C" void kernel_launch(void* const* d_in, const int* in_sizes, int n_in,
                              void* d_out, int out_size, void* d_ws, size_t ws_size,
                              hipStream_t stream) {
    const float* hs     = (const float*)d_in[0];
    const float* qkv_w  = (const float*)d_in[1];
    const float* qkv_b  = (const float*)d_in[2];
    const float* proj_w = (const float*)d_in[3];
    const float* proj_b = (const float*)d_in[4];
    const float* rph    = (const float*)d_in[5];
    const float* rpw    = (const float*)d_in[6];
    float* out = (float*)d_out;

    const size_t GQ = (size_t)64 * 1568 * 64;  // elems per Q/K/V
    const size_t N_HS = (size_t)6272 * 1024;
    const size_t N_QW = (size_t)3072 * 1024;
    const size_t N_PW = (size_t)1024 * 1024;
    bf16* Qb = (bf16*)d_ws;                    // [g][pix][64]
    bf16* Kb = Qb + GQ;                        // [g][pix][64]
    bf16* Vt = Kb + GQ;                        // [g][d][ppix] (permuted keys)
    bf16* AO = Vt + GQ;                        // [6272][1024]
    bf16* hs_bf    = AO + GQ;
    bf16* qkvw_bf  = hs_bf + N_HS;
    bf16* projw_bf = qkvw_bf + N_QW;
    const size_t need = (4 * GQ + N_HS + N_QW + N_PW) * sizeof(bf16); // 72.6 MB

    if (ws_size >= need) {
        cvt_kernel<<<512, 256, 0, stream>>>(hs, hs_bf, (int)(N_HS / 4));
        cvt_kernel<<<512, 256, 0, stream>>>(qkv_w, qkvw_bf, (int)(N_QW / 4));
        cvt_kernel<<<256, 256, 0, stream>>>(proj_w, projw_bf, (int)(N_PW / 4));
        qkv_gemm_bf16<<<dim3(49, 24), 256, 0, stream>>>(hs_bf, qkvw_bf, qkv_b, Qb, Kb, Vt);
        flash_attn<<<1600, 256, 0, stream>>>(Qb, Kb, Vt, rph, rpw, AO);
        proj_gemm_bf16<<<dim3(49, 8), 256, 0, stream>>>(AO, projw_bf, proj_b, out);
    } else {
        qkv_gemm_f32<<<dim3(49, 24), 256, 0, stream>>>(hs, qkv_w, qkv_b, Qb, Kb, Vt);
        flash_attn<<<1600, 256, 0, stream>>>(Qb, Kb, Vt, rph, rpw, AO);
        proj_gemm_f32<<<dim3(49, 8), 256, 0, stream>>>(AO, proj_w, proj_b, out);
    }
}

// Round 7
// 353.952 us; speedup vs baseline: 3.2701x; 1.6047x over previous
//
#include <hip/hip_runtime.h>
#include <hip/hip_bf16.h>
#include <stdint.h>

typedef __bf16 bf16;
typedef __bf16 bf16x2 __attribute__((ext_vector_type(2)));
typedef __bf16 bf16x4 __attribute__((ext_vector_type(4)));
typedef __bf16 bf16x8 __attribute__((ext_vector_type(8)));
typedef float f32x4 __attribute__((ext_vector_type(4)));

#define AS1 __attribute__((address_space(1)))
#define AS3 __attribute__((address_space(3)))

static __device__ __forceinline__ float b2f(bf16 x) { return (float)x; }

static __device__ __forceinline__ void async_cp16(const bf16* g, bf16* l) {
    __builtin_amdgcn_global_load_lds((const AS1 void*)g, (AS3 void*)l, 16, 0, 0);
}

static __device__ __forceinline__ bf16x4 cvt4(f32x4 v) {
    bf16x4 r;
    r[0] = (bf16)v[0]; r[1] = (bf16)v[1]; r[2] = (bf16)v[2]; r[3] = (bf16)v[3];
    return r;
}

// ---------------------------------------------------------------------------
// fp32 -> bf16 bulk convert (grid-stride, float4)
__global__ __launch_bounds__(256) void cvt_kernel(
    const float* __restrict__ src, bf16* __restrict__ dst, int n4) {
    int i = blockIdx.x * 256 + threadIdx.x;
    const int stride = gridDim.x * 256;
    for (; i < n4; i += stride)
        ((bf16x4*)dst)[i] = cvt4(((const f32x4*)src)[i]);
}

// NOTE: epilogue is INLINED in both qkv kernels. Round 5 passed acc[4][4]
// into a helper; array-decay defeated SROA -> acc lived in scratch -> every
// MFMA accumulate became a global-memory RMW (VGPR_Count 84, WRITE_SIZE
// 2.18 GB, 700 us). Do not refactor accumulators through pointers.

#define QKV_EPILOGUE()                                                        \
    for (int nt = 0; nt < 4; nt++) {                                          \
        const int n_ = n0 + wn + nt * 16 + lm;                                \
        const float bv = bias[n_];                                            \
        const int s = n_ >> 10, rem = n_ & 1023;                              \
        const int h = rem >> 6, d = rem & 63;                                 \
        for (int mt = 0; mt < 4; mt++) {                                      \
            for (int r = 0; r < 4; r++) {                                     \
                const int m_ = m0 + wm + mt * 16 + quad * 4 + r;              \
                const int b = m_ / 1568;                                      \
                const int pix = m_ - b * 1568;                                \
                const int g = b * 16 + h;                                     \
                const bf16 v = (bf16)(acc[mt][nt][r] + bv);                   \
                if (s == 0)      Qb[((size_t)g * 1568 + pix) * 64 + d] = v;   \
                else if (s == 1) Kb[((size_t)g * 1568 + pix) * 64 + d] = v;   \
                else {                                                        \
                    const int lk = pix & 31;                                  \
                    const int ppix = (pix & ~31) | ((lk & 15) << 1) | (lk >> 4); \
                    Vt[((size_t)g * 64 + d) * 1568 + ppix] = v;               \
                }                                                             \
            }                                                                 \
        }                                                                     \
    }

// ---------------------------------------------------------------------------
// Kernel 1a: QKV projection, bf16 inputs (pre-converted), m97 async staging.
__global__ __launch_bounds__(256) void qkv_gemm_bf16(
    const bf16* __restrict__ A, const bf16* __restrict__ W,
    const float* __restrict__ bias, bf16* __restrict__ Qb,
    bf16* __restrict__ Kb, bf16* __restrict__ Vt) {
    __shared__ bf16 As[128 * 32];
    __shared__ bf16 Bs[128 * 32];
    const int t = threadIdx.x;
    const int wid = t >> 6, lane = t & 63;
    const int m0 = blockIdx.x * 128, n0 = blockIdx.y * 128;
    const int wm = (wid & 1) * 64, wn = (wid >> 1) * 64;
    const int r_i = lane >> 2, c8 = (lane & 3) * 8;
    const int lm = lane & 15, quad = lane >> 4;

    f32x4 acc[4][4] = {};
    for (int k0 = 0; k0 < 1024; k0 += 32) {
        __syncthreads();
        for (int i = 0; i < 2; i++) {
            const int blk = wid * 2 + i;
            async_cp16(A + (size_t)(m0 + blk * 16 + r_i) * 1024 + k0 + c8, As + blk * 512);
            async_cp16(W + (size_t)(n0 + blk * 16 + r_i) * 1024 + k0 + c8, Bs + blk * 512);
        }
        __syncthreads();
        bf16x8 af[4], bfr[4];
        for (int x = 0; x < 4; x++) {
            af[x]  = *(const bf16x8*)&As[(wm + x * 16 + lm) * 32 + quad * 8];
            bfr[x] = *(const bf16x8*)&Bs[(wn + x * 16 + lm) * 32 + quad * 8];
        }
        for (int mt = 0; mt < 4; mt++)
            for (int nt = 0; nt < 4; nt++)
                acc[mt][nt] = __builtin_amdgcn_mfma_f32_16x16x32_bf16(af[mt], bfr[nt], acc[mt][nt], 0, 0, 0);
    }
    QKV_EPILOGUE()
}

// Kernel 1b: fallback — fp32 inputs, convert at LDS-stage time.
__global__ __launch_bounds__(256) void qkv_gemm_f32(
    const float* __restrict__ A, const float* __restrict__ W,
    const float* __restrict__ bias, bf16* __restrict__ Qb,
    bf16* __restrict__ Kb, bf16* __restrict__ Vt) {
    __shared__ bf16 As[128 * 32];
    __shared__ bf16 Bs[128 * 32];
    const int t = threadIdx.x;
    const int wid = t >> 6, lane = t & 63;
    const int m0 = blockIdx.x * 128, n0 = blockIdx.y * 128;
    const int wm = (wid & 1) * 64, wn = (wid >> 1) * 64;
    const int lm = lane & 15, quad = lane >> 4;

    f32x4 acc[4][4] = {};
    for (int k0 = 0; k0 < 1024; k0 += 32) {
        __syncthreads();
        for (int i = 0; i < 4; i++) {
            const int idx = t + i * 256;
            const int row = idx >> 3, c4 = (idx & 7) * 4;
            const f32x4 av = *(const f32x4*)&A[(size_t)(m0 + row) * 1024 + k0 + c4];
            const f32x4 wv = *(const f32x4*)&W[(size_t)(n0 + row) * 1024 + k0 + c4];
            *(bf16x4*)&As[row * 32 + c4] = cvt4(av);
            *(bf16x4*)&Bs[row * 32 + c4] = cvt4(wv);
        }
        __syncthreads();
        bf16x8 af[4], bfr[4];
        for (int x = 0; x < 4; x++) {
            af[x]  = *(const bf16x8*)&As[(wm + x * 16 + lm) * 32 + quad * 8];
            bfr[x] = *(const bf16x8*)&Bs[(wn + x * 16 + lm) * 32 + quad * 8];
        }
        for (int mt = 0; mt < 4; mt++)
            for (int nt = 0; nt < 4; nt++)
                acc[mt][nt] = __builtin_amdgcn_mfma_f32_16x16x32_bf16(af[mt], bfr[nt], acc[mt][nt], 0, 0, 0);
    }
    QKV_EPILOGUE()
}

// ---------------------------------------------------------------------------
// Kernel 2: flash attention. Rel-pos bias tables T_h[ql][i]=Q[ql].rph[i],
// T_w[ql][i]=Q[ql].rpw[i] computed in the prologue via MFMA from LDS-staged
// (coalesced, once-per-block) rp tables — replaces the per-thread scattered
// dot products that serialized the TA/L1 path. T rows padded (114/58) so the
// 4 quads of a wave read distinct banks (old stride 224B = 0 mod 32 banks was
// the constant 2.1e7 SQ_LDS_BANK_CONFLICT). Fixed-shift softmax; register
// prefetch of K/V tiles; XCD-swizzled grid.
__global__ __launch_bounds__(256) void flash_attn(
    const bf16* __restrict__ Qb, const bf16* __restrict__ Kb,
    const bf16* __restrict__ Vt, const float* __restrict__ rph,
    const float* __restrict__ rpw, bf16* __restrict__ AO) {
    const int x = blockIdx.x;
    const int xcd = x & 7, j = x >> 3;          // j in 0..199
    const int g = xcd * 8 + j / 25;
    const int qblk = j - (j / 25) * 25;
    const int q0 = qblk * 64;

    // LDS: region A = T tables (live whole kernel); region B multi-use:
    // prologue {Qs | RPh | RPw}, loop {Ks,Vts,Ps}. 38400 B -> 4 blocks/CU.
    __shared__ __align__(16) char smem[38400];
    bf16* Th  = (bf16*)smem;                // [64][114] bf16 (cols 0..111 used)
    bf16* Tw  = (bf16*)(smem + 14592);      // [64][58]  bf16 (cols 0..54 used)
    char* B   = smem + 22016;               // 16384 B region
    bf16* Qs  = (bf16*)B;                   // [64][72]  prologue phase 0
    bf16* RPs = (bf16*)B;                   // [112][72] prologue phases 1-2
    bf16* Ks  = (bf16*)B;                   // [32][72]  loop
    bf16* Vts = (bf16*)(B + 4608);          // [64][40]  loop (permuted keys)
    bf16* Ps  = (bf16*)(B + 9728);          // [4][16][40] loop

    const int t = threadIdx.x, wid = t >> 6, lane = t & 63;
    const int lm = lane & 15, quad = lane >> 4;
    const int qbase_l = wid * 16 + quad * 4;

    // phase 0: stage Q tile [64][64] -> LDS (rows clamped for the q tail)
    for (int c = t; c < 512; c += 256) {
        const int row = c >> 3, col = (c & 7) * 8;
        const int qg = min(q0 + row, 1567);
        *(bf16x8*)&Qs[row * 72 + col] =
            *(const bf16x8*)&Qb[((size_t)g * 1568 + qg) * 64 + col];
    }
    __syncthreads();
    const int qrow_l = wid * 16 + lm;
    const bf16x8 qf0 = *(const bf16x8*)&Qs[qrow_l * 72 + quad * 8];
    const bf16x8 qf1 = *(const bf16x8*)&Qs[qrow_l * 72 + 32 + quad * 8];
    // per-lane bias index bases
    int ihb[4], iwb[4];
#pragma unroll
    for (int r = 0; r < 4; r++) {
        const int qg = min(q0 + qbase_l + r, 1567);
        const int hq = qg / 28;
        ihb[r] = hq + 55;
        iwb[r] = (qg - hq * 28) + 27;
    }
    __syncthreads();  // all Qs reads done before RPh overwrites

    // phase 1: stage rph (111x64 fp32 -> bf16, coalesced), T_h MFMA
    for (int c = t; c < 1776; c += 256) {       // 111*64/4
        const int row = c >> 4, col = (c & 15) * 4;
        *(bf16x4*)&RPs[row * 72 + col] = cvt4(*(const f32x4*)&rph[row * 64 + col]);
    }
    __syncthreads();
    f32x4 acch[7];
#pragma unroll
    for (int nt = 0; nt < 7; nt++) {
        const bf16x8 b0 = *(const bf16x8*)&RPs[(nt * 16 + lm) * 72 + quad * 8];
        const bf16x8 b1 = *(const bf16x8*)&RPs[(nt * 16 + lm) * 72 + 32 + quad * 8];
        f32x4 a = {};
        a = __builtin_amdgcn_mfma_f32_16x16x32_bf16(qf0, b0, a, 0, 0, 0);
        a = __builtin_amdgcn_mfma_f32_16x16x32_bf16(qf1, b1, a, 0, 0, 0);
        acch[nt] = a;
    }
    __syncthreads();  // all RPh reads done before RPw overwrites

    // phase 2: stage rpw (55x64), write T_h, T_w MFMA + write
    for (int c = t; c < 880; c += 256) {        // 55*64/4
        const int row = c >> 4, col = (c & 15) * 4;
        *(bf16x4*)&RPs[row * 72 + col] = cvt4(*(const f32x4*)&rpw[row * 64 + col]);
    }
#pragma unroll
    for (int nt = 0; nt < 7; nt++)
#pragma unroll
        for (int r = 0; r < 4; r++)
            Th[(qbase_l + r) * 114 + nt * 16 + lm] = (bf16)acch[nt][r];
    __syncthreads();
#pragma unroll
    for (int nt = 0; nt < 4; nt++) {
        const bf16x8 b0 = *(const bf16x8*)&RPs[(nt * 16 + lm) * 72 + quad * 8];
        const bf16x8 b1 = *(const bf16x8*)&RPs[(nt * 16 + lm) * 72 + 32 + quad * 8];
        f32x4 a = {};
        a = __builtin_amdgcn_mfma_f32_16x16x32_bf16(qf0, b0, a, 0, 0, 0);
        a = __builtin_amdgcn_mfma_f32_16x16x32_bf16(qf1, b1, a, 0, 0, 0);
        const int col = nt * 16 + lm;
        if (col < 58) {
#pragma unroll
            for (int r = 0; r < 4; r++)
                Tw[(qbase_l + r) * 58 + col] = (bf16)a[r];
        }
    }
    // loop's first __syncthreads covers: RPw reads + T writes vs Ks staging.

    f32x4 o[4] = {};
    float l_lane[4] = {0.f, 0.f, 0.f, 0.f};
    const float scale = 0.125f;
    const float SHIFT = 10.0f;

    const int ks_k = t >> 3, ks_d = (t & 7) * 8;   // K staging coords
    const int vs_d = t >> 2, vs_k = (t & 3) * 8;   // Vt staging coords
    bf16* Pw = &Ps[wid * 640];

    // incremental hk/wk for key0 = kt*32+lm, key1 = key0+16
    int hk0 = 0, wk0 = lm;
    int hk1 = (16 + lm) >= 28 ? 1 : 0;
    int wk1 = 16 + lm - (hk1 ? 28 : 0);

    // register prefetch of tile 0
    const size_t kgbase = ((size_t)g * 1568 + ks_k) * 64 + ks_d;
    const size_t vgbase = ((size_t)g * 64 + vs_d) * 1568 + vs_k;
    bf16x8 kreg = *(const bf16x8*)&Kb[kgbase];
    bf16x8 vreg = *(const bf16x8*)&Vt[vgbase];

    for (int kt = 0; kt < 49; kt++) {
        __syncthreads();                           // prev tile's readers done
        *(bf16x8*)&Ks[ks_k * 72 + ks_d] = kreg;
        *(bf16x8*)&Vts[vs_d * 40 + vs_k] = vreg;
        if (kt + 1 < 49) {                         // next tile's loads retire
            kreg = *(const bf16x8*)&Kb[kgbase + (size_t)(kt + 1) * 2048];
            vreg = *(const bf16x8*)&Vt[vgbase + (kt + 1) * 32];
        }
        __syncthreads();

        // S = Q K^T  (two 16-key fragments)
        f32x4 s0 = {}, s1 = {};
        {
            const bf16x8 ka0 = *(const bf16x8*)&Ks[lm * 72 + quad * 8];
            const bf16x8 ka1 = *(const bf16x8*)&Ks[lm * 72 + 32 + quad * 8];
            s0 = __builtin_amdgcn_mfma_f32_16x16x32_bf16(qf0, ka0, s0, 0, 0, 0);
            s0 = __builtin_amdgcn_mfma_f32_16x16x32_bf16(qf1, ka1, s0, 0, 0, 0);
            const bf16x8 kb0 = *(const bf16x8*)&Ks[(16 + lm) * 72 + quad * 8];
            const bf16x8 kb1 = *(const bf16x8*)&Ks[(16 + lm) * 72 + 32 + quad * 8];
            s1 = __builtin_amdgcn_mfma_f32_16x16x32_bf16(qf0, kb0, s1, 0, 0, 0);
            s1 = __builtin_amdgcn_mfma_f32_16x16x32_bf16(qf1, kb1, s1, 0, 0, 0);
        }

        // bias (conflict-free T reads) + fixed-shift exp; P packed bf16x2
#pragma unroll
        for (int r = 0; r < 4; r++) {
            const int ql = qbase_l + r;
            const float p0 = __expf(s0[r] * scale + b2f(Th[ql * 114 + ihb[r] - hk0])
                                    + b2f(Tw[ql * 58 + iwb[r] - wk0]) - SHIFT);
            const float p1 = __expf(s1[r] * scale + b2f(Th[ql * 114 + ihb[r] - hk1])
                                    + b2f(Tw[ql * 58 + iwb[r] - wk1]) - SHIFT);
            l_lane[r] += p0 + p1;
            bf16x2 pp; pp[0] = (bf16)p0; pp[1] = (bf16)p1;
            *(bf16x2*)&Pw[(quad * 4 + r) * 40 + lm * 2] = pp;
        }
        // advance keys by 32: 32 = 28 + 4
        wk0 += 4; hk0 += 1; if (wk0 >= 28) { wk0 -= 28; hk0 += 1; }
        wk1 += 4; hk1 += 1; if (wk1 >= 28) { wk1 -= 28; hk1 += 1; }

        __asm__ volatile("s_waitcnt lgkmcnt(0)" ::: "memory");
        const bf16x8 pf = *(const bf16x8*)&Pw[lm * 40 + quad * 8];
#pragma unroll
        for (int dt = 0; dt < 4; dt++) {
            const bf16x8 vf = *(const bf16x8*)&Vts[(dt * 16 + lm) * 40 + quad * 8];
            o[dt] = __builtin_amdgcn_mfma_f32_16x16x32_bf16(pf, vf, o[dt], 0, 0, 0);
        }
    }

    // single l reduction (16 lanes per row group), then epilogue
    const int qrow0 = q0 + qbase_l;
    if (q0 + wid * 16 < 1568) {
        const int bo = g >> 4, h = g & 15;
#pragma unroll
        for (int r = 0; r < 4; r++) {
            float ll = l_lane[r];
            for (int off = 1; off < 16; off <<= 1) ll += __shfl_xor(ll, off, 64);
            const float inv = 1.0f / ll;
            const size_t base = ((size_t)bo * 1568 + qrow0 + r) * 1024 + h * 64;
            for (int dt = 0; dt < 4; dt++)
                AO[base + dt * 16 + lm] = (bf16)(o[dt][r] * inv);
        }
    }
}

// ---------------------------------------------------------------------------
// Kernel 3a: output projection, both operands bf16 (W pre-converted).
__global__ __launch_bounds__(256) void proj_gemm_bf16(
    const bf16* __restrict__ A, const bf16* __restrict__ W,
    const float* __restrict__ bias, float* __restrict__ out) {
    __shared__ bf16 As[128 * 32];
    __shared__ bf16 Bs[128 * 32];
    const int t = threadIdx.x;
    const int wid = t >> 6, lane = t & 63;
    const int m0 = blockIdx.x * 128, n0 = blockIdx.y * 128;
    const int wm = (wid & 1) * 64, wn = (wid >> 1) * 64;
    const int r_i = lane >> 2, c8 = (lane & 3) * 8;
    const int lm = lane & 15, quad = lane >> 4;

    f32x4 acc[4][4] = {};
    for (int k0 = 0; k0 < 1024; k0 += 32) {
        __syncthreads();
        for (int i = 0; i < 2; i++) {
            const int blk = wid * 2 + i;
            async_cp16(A + (size_t)(m0 + blk * 16 + r_i) * 1024 + k0 + c8, As + blk * 512);
            async_cp16(W + (size_t)(n0 + blk * 16 + r_i) * 1024 + k0 + c8, Bs + blk * 512);
        }
        __syncthreads();
        bf16x8 af[4], bfr[4];
        for (int x = 0; x < 4; x++) {
            af[x]  = *(const bf16x8*)&As[(wm + x * 16 + lm) * 32 + quad * 8];
            bfr[x] = *(const bf16x8*)&Bs[(wn + x * 16 + lm) * 32 + quad * 8];
        }
        for (int mt = 0; mt < 4; mt++)
            for (int nt = 0; nt < 4; nt++)
                acc[mt][nt] = __builtin_amdgcn_mfma_f32_16x16x32_bf16(af[mt], bfr[nt], acc[mt][nt], 0, 0, 0);
    }
    for (int nt = 0; nt < 4; nt++) {
        const int n_ = n0 + wn + nt * 16 + lm;
        const float bv = bias[n_];
        for (int mt = 0; mt < 4; mt++)
            for (int r = 0; r < 4; r++) {
                const int m_ = m0 + wm + mt * 16 + quad * 4 + r;
                out[(size_t)m_ * 1024 + n_] = acc[mt][nt][r] + bv;
            }
    }
}

// Kernel 3b: fallback — W fp32, converted at stage time.
__global__ __launch_bounds__(256) void proj_gemm_f32(
    const bf16* __restrict__ A, const float* __restrict__ W,
    const float* __restrict__ bias, float* __restrict__ out) {
    __shared__ bf16 As[128 * 32];
    __shared__ bf16 Bs[128 * 32];
    const int t = threadIdx.x;
    const int wid = t >> 6, lane = t & 63;
    const int m0 = blockIdx.x * 128, n0 = blockIdx.y * 128;
    const int wm = (wid & 1) * 64, wn = (wid >> 1) * 64;
    const int r_i = lane >> 2, c8 = (lane & 3) * 8;
    const int lm = lane & 15, quad = lane >> 4;

    f32x4 acc[4][4] = {};
    for (int k0 = 0; k0 < 1024; k0 += 32) {
        __syncthreads();
        for (int i = 0; i < 2; i++) {
            const int blk = wid * 2 + i;
            async_cp16(A + (size_t)(m0 + blk * 16 + r_i) * 1024 + k0 + c8, As + blk * 512);
        }
        for (int i = 0; i < 4; i++) {
            const int idx = t + i * 256;
            const int row = idx >> 3, c4 = (idx & 7) * 4;
            const f32x4 wv = *(const f32x4*)&W[(size_t)(n0 + row) * 1024 + k0 + c4];
            *(bf16x4*)&Bs[row * 32 + c4] = cvt4(wv);
        }
        __syncthreads();
        bf16x8 af[4], bfr[4];
        for (int x = 0; x < 4; x++) {
            af[x]  = *(const bf16x8*)&As[(wm + x * 16 + lm) * 32 + quad * 8];
            bfr[x] = *(const bf16x8*)&Bs[(wn + x * 16 + lm) * 32 + quad * 8];
        }
        for (int mt = 0; mt < 4; mt++)
            for (int nt = 0; nt < 4; nt++)
                acc[mt][nt] = __builtin_amdgcn_mfma_f32_16x16x32_bf16(af[mt], bfr[nt], acc[mt][nt], 0, 0, 0);
    }
    for (int nt = 0; nt < 4; nt++) {
        const int n_ = n0 + wn + nt * 16 + lm;
        const float bv = bias[n_];
        for (int mt = 0; mt < 4; mt++)
            for (int r = 0; r < 4; r++) {
                const int m_ = m0 + wm + mt * 16 + quad * 4 + r;
                out[(size_t)m_ * 1024 + n_] = acc[mt][nt][r] + bv;
            }
    }
}

// ---------------------------------------------------------------------------
extern "C" void kernel_launch(void* const* d_in, const int* in_sizes, int n_in,
                              void* d_out, int out_size, void* d_ws, size_t ws_size,
                              hipStream_t stream) {
    const float* hs     = (const float*)d_in[0];
    const float* qkv_w  = (const float*)d_in[1];
    const float* qkv_b  = (const float*)d_in[2];
    const float* proj_w = (const float*)d_in[3];
    const float* proj_b = (const float*)d_in[4];
    const float* rph    = (const float*)d_in[5];
    const float* rpw    = (const float*)d_in[6];
    float* out = (float*)d_out;

    const size_t GQ = (size_t)64 * 1568 * 64;  // elems per Q/K/V
    const size_t N_HS = (size_t)6272 * 1024;
    const size_t N_QW = (size_t)3072 * 1024;
    const size_t N_PW = (size_t)1024 * 1024;
    bf16* Qb = (bf16*)d_ws;                    // [g][pix][64]
    bf16* Kb = Qb + GQ;                        // [g][pix][64]
    bf16* Vt = Kb + GQ;                        // [g][d][ppix] (permuted keys)
    bf16* AO = Vt + GQ;                        // [6272][1024]
    bf16* hs_bf    = AO + GQ;
    bf16* qkvw_bf  = hs_bf + N_HS;
    bf16* projw_bf = qkvw_bf + N_QW;
    const size_t need = (4 * GQ + N_HS + N_QW + N_PW) * sizeof(bf16); // 72.6 MB

    if (ws_size >= need) {
        cvt_kernel<<<512, 256, 0, stream>>>(hs, hs_bf, (int)(N_HS / 4));
        cvt_kernel<<<512, 256, 0, stream>>>(qkv_w, qkvw_bf, (int)(N_QW / 4));
        cvt_kernel<<<256, 256, 0, stream>>>(proj_w, projw_bf, (int)(N_PW / 4));
        qkv_gemm_bf16<<<dim3(49, 24), 256, 0, stream>>>(hs_bf, qkvw_bf, qkv_b, Qb, Kb, Vt);
        flash_attn<<<1600, 256, 0, stream>>>(Qb, Kb, Vt, rph, rpw, AO);
        proj_gemm_bf16<<<dim3(49, 8), 256, 0, stream>>>(AO, projw_bf, proj_b, out);
    } else {
        qkv_gemm_f32<<<dim3(49, 24), 256, 0, stream>>>(hs, qkv_w, qkv_b, Qb, Kb, Vt);
        flash_attn<<<1600, 256, 0, stream>>>(Qb, Kb, Vt, rph, rpw, AO);
        proj_gemm_f32<<<dim3(49, 8), 256, 0, stream>>>(AO, proj_w, proj_b, out);
    }
}

// Round 8
// 348.203 us; speedup vs baseline: 3.3241x; 1.0165x over previous
//
#include <hip/hip_runtime.h>
#include <hip/hip_bf16.h>
#include <stdint.h>

typedef __bf16 bf16;
typedef __bf16 bf16x2 __attribute__((ext_vector_type(2)));
typedef __bf16 bf16x4 __attribute__((ext_vector_type(4)));
typedef __bf16 bf16x8 __attribute__((ext_vector_type(8)));
typedef float f32x4 __attribute__((ext_vector_type(4)));

#define AS1 __attribute__((address_space(1)))
#define AS3 __attribute__((address_space(3)))

static __device__ __forceinline__ float b2f(bf16 x) { return (float)x; }

static __device__ __forceinline__ void async_cp16(const bf16* g, bf16* l) {
    __builtin_amdgcn_global_load_lds((const AS1 void*)g, (AS3 void*)l, 16, 0, 0);
}

static __device__ __forceinline__ bf16x4 cvt4(f32x4 v) {
    bf16x4 r;
    r[0] = (bf16)v[0]; r[1] = (bf16)v[1]; r[2] = (bf16)v[2]; r[3] = (bf16)v[3];
    return r;
}

static __device__ __forceinline__ float fast_exp2(float x) {
#if __has_builtin(__builtin_amdgcn_exp2f)
    return __builtin_amdgcn_exp2f(x);
#else
    return __expf(x * 0.69314718056f);
#endif
}

// ---------------------------------------------------------------------------
// fp32 -> bf16 bulk convert (grid-stride, float4)
__global__ __launch_bounds__(256) void cvt_kernel(
    const float* __restrict__ src, bf16* __restrict__ dst, int n4) {
    int i = blockIdx.x * 256 + threadIdx.x;
    const int stride = gridDim.x * 256;
    for (; i < n4; i += stride)
        ((bf16x4*)dst)[i] = cvt4(((const f32x4*)src)[i]);
}

// NOTE: epilogue is INLINED in both qkv kernels. Round 5 passed acc[4][4]
// into a helper; array-decay defeated SROA -> acc lived in scratch -> every
// MFMA accumulate became a global-memory RMW (VGPR_Count 84, WRITE_SIZE
// 2.18 GB, 700 us). Do not refactor accumulators through pointers.

#define QKV_EPILOGUE()                                                        \
    for (int nt = 0; nt < 4; nt++) {                                          \
        const int n_ = n0 + wn + nt * 16 + lm;                                \
        const float bv = bias[n_];                                            \
        const int s = n_ >> 10, rem = n_ & 1023;                              \
        const int h = rem >> 6, d = rem & 63;                                 \
        for (int mt = 0; mt < 4; mt++) {                                      \
            for (int r = 0; r < 4; r++) {                                     \
                const int m_ = m0 + wm + mt * 16 + quad * 4 + r;              \
                const int b = m_ / 1568;                                      \
                const int pix = m_ - b * 1568;                                \
                const int g = b * 16 + h;                                     \
                const bf16 v = (bf16)(acc[mt][nt][r] + bv);                   \
                if (s == 0)      Qb[((size_t)g * 1568 + pix) * 64 + d] = v;   \
                else if (s == 1) Kb[((size_t)g * 1568 + pix) * 64 + d] = v;   \
                else {                                                        \
                    const int lk = pix & 31;                                  \
                    const int ppix = (pix & ~31) | ((lk & 15) << 1) | (lk >> 4); \
                    Vt[((size_t)g * 64 + d) * 1568 + ppix] = v;               \
                }                                                             \
            }                                                                 \
        }                                                                     \
    }

// ---------------------------------------------------------------------------
// Kernel 1a: QKV projection, bf16 inputs (pre-converted), m97 async staging.
__global__ __launch_bounds__(256) void qkv_gemm_bf16(
    const bf16* __restrict__ A, const bf16* __restrict__ W,
    const float* __restrict__ bias, bf16* __restrict__ Qb,
    bf16* __restrict__ Kb, bf16* __restrict__ Vt) {
    __shared__ bf16 As[128 * 32];
    __shared__ bf16 Bs[128 * 32];
    const int t = threadIdx.x;
    const int wid = t >> 6, lane = t & 63;
    const int m0 = blockIdx.x * 128, n0 = blockIdx.y * 128;
    const int wm = (wid & 1) * 64, wn = (wid >> 1) * 64;
    const int r_i = lane >> 2, c8 = (lane & 3) * 8;
    const int lm = lane & 15, quad = lane >> 4;

    f32x4 acc[4][4] = {};
    for (int k0 = 0; k0 < 1024; k0 += 32) {
        __syncthreads();
        for (int i = 0; i < 2; i++) {
            const int blk = wid * 2 + i;
            async_cp16(A + (size_t)(m0 + blk * 16 + r_i) * 1024 + k0 + c8, As + blk * 512);
            async_cp16(W + (size_t)(n0 + blk * 16 + r_i) * 1024 + k0 + c8, Bs + blk * 512);
        }
        __syncthreads();
        bf16x8 af[4], bfr[4];
        for (int x = 0; x < 4; x++) {
            af[x]  = *(const bf16x8*)&As[(wm + x * 16 + lm) * 32 + quad * 8];
            bfr[x] = *(const bf16x8*)&Bs[(wn + x * 16 + lm) * 32 + quad * 8];
        }
        for (int mt = 0; mt < 4; mt++)
            for (int nt = 0; nt < 4; nt++)
                acc[mt][nt] = __builtin_amdgcn_mfma_f32_16x16x32_bf16(af[mt], bfr[nt], acc[mt][nt], 0, 0, 0);
    }
    QKV_EPILOGUE()
}

// Kernel 1b: fallback — fp32 inputs, convert at LDS-stage time.
__global__ __launch_bounds__(256) void qkv_gemm_f32(
    const float* __restrict__ A, const float* __restrict__ W,
    const float* __restrict__ bias, bf16* __restrict__ Qb,
    bf16* __restrict__ Kb, bf16* __restrict__ Vt) {
    __shared__ bf16 As[128 * 32];
    __shared__ bf16 Bs[128 * 32];
    const int t = threadIdx.x;
    const int wid = t >> 6, lane = t & 63;
    const int m0 = blockIdx.x * 128, n0 = blockIdx.y * 128;
    const int wm = (wid & 1) * 64, wn = (wid >> 1) * 64;
    const int lm = lane & 15, quad = lane >> 4;

    f32x4 acc[4][4] = {};
    for (int k0 = 0; k0 < 1024; k0 += 32) {
        __syncthreads();
        for (int i = 0; i < 4; i++) {
            const int idx = t + i * 256;
            const int row = idx >> 3, c4 = (idx & 7) * 4;
            const f32x4 av = *(const f32x4*)&A[(size_t)(m0 + row) * 1024 + k0 + c4];
            const f32x4 wv = *(const f32x4*)&W[(size_t)(n0 + row) * 1024 + k0 + c4];
            *(bf16x4*)&As[row * 32 + c4] = cvt4(av);
            *(bf16x4*)&Bs[row * 32 + c4] = cvt4(wv);
        }
        __syncthreads();
        bf16x8 af[4], bfr[4];
        for (int x = 0; x < 4; x++) {
            af[x]  = *(const bf16x8*)&As[(wm + x * 16 + lm) * 32 + quad * 8];
            bfr[x] = *(const bf16x8*)&Bs[(wn + x * 16 + lm) * 32 + quad * 8];
        }
        for (int mt = 0; mt < 4; mt++)
            for (int nt = 0; nt < 4; nt++)
                acc[mt][nt] = __builtin_amdgcn_mfma_f32_16x16x32_bf16(af[mt], bfr[nt], acc[mt][nt], 0, 0, 0);
    }
    QKV_EPILOGUE()
}

// ---------------------------------------------------------------------------
// Kernel 2: flash attention. T tables hold 8*(Q.rp) in bf16; the rel-pos bias
// is pre-added into the QK MFMA C-input (off the post-MFMA critical path),
// and softmax is p = exp2(fma(s, 0.125*log2e, -10*log2e)) — 1 fma + 1 hw
// exp2 per element. Fixed-shift softmax (no running max); register prefetch
// of K/V tiles; XCD-swizzled grid.
__global__ __launch_bounds__(256) void flash_attn(
    const bf16* __restrict__ Qb, const bf16* __restrict__ Kb,
    const bf16* __restrict__ Vt, const float* __restrict__ rph,
    const float* __restrict__ rpw, bf16* __restrict__ AO) {
    const int x = blockIdx.x;
    const int xcd = x & 7, j = x >> 3;          // j in 0..199
    const int g = xcd * 8 + j / 25;
    const int qblk = j - (j / 25) * 25;
    const int q0 = qblk * 64;

    // LDS: region A = T tables (live whole kernel); region B multi-use:
    // prologue {Qs | RPh | RPw}, loop {Ks,Vts,Ps}. 38400 B -> 4 blocks/CU.
    __shared__ __align__(16) char smem[38400];
    bf16* Th  = (bf16*)smem;                // [64][114] bf16, values 8*th
    bf16* Tw  = (bf16*)(smem + 14592);      // [64][58]  bf16, values 8*tw
    char* B   = smem + 22016;               // 16384 B region
    bf16* Qs  = (bf16*)B;                   // [64][72]  prologue phase 0
    bf16* RPs = (bf16*)B;                   // [112][72] prologue phases 1-2
    bf16* Ks  = (bf16*)B;                   // [32][72]  loop
    bf16* Vts = (bf16*)(B + 4608);          // [64][40]  loop (permuted keys)
    bf16* Ps  = (bf16*)(B + 9728);          // [4][16][40] loop

    const int t = threadIdx.x, wid = t >> 6, lane = t & 63;
    const int lm = lane & 15, quad = lane >> 4;
    const int qbase_l = wid * 16 + quad * 4;

    // phase 0: stage Q tile [64][64] -> LDS (rows clamped for the q tail)
    for (int c = t; c < 512; c += 256) {
        const int row = c >> 3, col = (c & 7) * 8;
        const int qg = min(q0 + row, 1567);
        *(bf16x8*)&Qs[row * 72 + col] =
            *(const bf16x8*)&Qb[((size_t)g * 1568 + qg) * 64 + col];
    }
    __syncthreads();
    const int qrow_l = wid * 16 + lm;
    const bf16x8 qf0 = *(const bf16x8*)&Qs[qrow_l * 72 + quad * 8];
    const bf16x8 qf1 = *(const bf16x8*)&Qs[qrow_l * 72 + 32 + quad * 8];
    // per-lane T-read element-index bases (loop subtracts hk/wk)
    int thb[4], twb[4];
#pragma unroll
    for (int r = 0; r < 4; r++) {
        const int qg = min(q0 + qbase_l + r, 1567);
        const int hq = qg / 28;
        thb[r] = (qbase_l + r) * 114 + hq + 55;
        twb[r] = (qbase_l + r) * 58 + (qg - hq * 28) + 27;
    }
    __syncthreads();  // all Qs reads done before RPh overwrites

    // phase 1: stage rph (111x64 fp32 -> bf16, coalesced), T_h MFMA
    for (int c = t; c < 1776; c += 256) {       // 111*64/4
        const int row = c >> 4, col = (c & 15) * 4;
        *(bf16x4*)&RPs[row * 72 + col] = cvt4(*(const f32x4*)&rph[row * 64 + col]);
    }
    __syncthreads();
    f32x4 acch[7];
#pragma unroll
    for (int nt = 0; nt < 7; nt++) {
        const bf16x8 b0 = *(const bf16x8*)&RPs[(nt * 16 + lm) * 72 + quad * 8];
        const bf16x8 b1 = *(const bf16x8*)&RPs[(nt * 16 + lm) * 72 + 32 + quad * 8];
        f32x4 a = {};
        a = __builtin_amdgcn_mfma_f32_16x16x32_bf16(qf0, b0, a, 0, 0, 0);
        a = __builtin_amdgcn_mfma_f32_16x16x32_bf16(qf1, b1, a, 0, 0, 0);
        acch[nt] = a;
    }
    __syncthreads();  // all RPh reads done before RPw overwrites

    // phase 2: stage rpw (55x64), write T_h (x8), T_w MFMA + write (x8)
    for (int c = t; c < 880; c += 256) {        // 55*64/4
        const int row = c >> 4, col = (c & 15) * 4;
        *(bf16x4*)&RPs[row * 72 + col] = cvt4(*(const f32x4*)&rpw[row * 64 + col]);
    }
#pragma unroll
    for (int nt = 0; nt < 7; nt++)
#pragma unroll
        for (int r = 0; r < 4; r++)
            Th[(qbase_l + r) * 114 + nt * 16 + lm] = (bf16)(acch[nt][r] * 8.0f);
    __syncthreads();
#pragma unroll
    for (int nt = 0; nt < 4; nt++) {
        const bf16x8 b0 = *(const bf16x8*)&RPs[(nt * 16 + lm) * 72 + quad * 8];
        const bf16x8 b1 = *(const bf16x8*)&RPs[(nt * 16 + lm) * 72 + 32 + quad * 8];
        f32x4 a = {};
        a = __builtin_amdgcn_mfma_f32_16x16x32_bf16(qf0, b0, a, 0, 0, 0);
        a = __builtin_amdgcn_mfma_f32_16x16x32_bf16(qf1, b1, a, 0, 0, 0);
        const int col = nt * 16 + lm;
        if (col < 58) {
#pragma unroll
            for (int r = 0; r < 4; r++)
                Tw[(qbase_l + r) * 58 + col] = (bf16)(a[r] * 8.0f);
        }
    }
    // loop's first __syncthreads covers: RPw reads + T writes vs Ks staging.

    f32x4 o[4] = {};
    float l_lane[4] = {0.f, 0.f, 0.f, 0.f};
    const float C2 = 0.125f * 1.44269504f;   // scale * log2(e)
    const float S2 = 10.0f * 1.44269504f;    // SHIFT * log2(e)

    const int ks_k = t >> 3, ks_d = (t & 7) * 8;   // K staging coords
    const int vs_d = t >> 2, vs_k = (t & 3) * 8;   // Vt staging coords
    bf16* Pw = &Ps[wid * 640];

    // incremental hk/wk for key0 = kt*32+lm, key1 = key0+16
    int hk0 = 0, wk0 = lm;
    int hk1 = (16 + lm) >= 28 ? 1 : 0;
    int wk1 = 16 + lm - (hk1 ? 28 : 0);

    // register prefetch of tile 0
    const size_t kgbase = ((size_t)g * 1568 + ks_k) * 64 + ks_d;
    const size_t vgbase = ((size_t)g * 64 + vs_d) * 1568 + vs_k;
    bf16x8 kreg = *(const bf16x8*)&Kb[kgbase];
    bf16x8 vreg = *(const bf16x8*)&Vt[vgbase];

    for (int kt = 0; kt < 49; kt++) {
        // rel-pos bias pre-added into the QK MFMA C-input (off the
        // post-MFMA chain; overlaps staging)
        f32x4 s0, s1;
#pragma unroll
        for (int r = 0; r < 4; r++) {
            s0[r] = b2f(Th[thb[r] - hk0]) + b2f(Tw[twb[r] - wk0]);
            s1[r] = b2f(Th[thb[r] - hk1]) + b2f(Tw[twb[r] - wk1]);
        }

        __syncthreads();                           // prev tile's readers done
        *(bf16x8*)&Ks[ks_k * 72 + ks_d] = kreg;
        *(bf16x8*)&Vts[vs_d * 40 + vs_k] = vreg;
        {
            const int ktn = min(kt + 1, 48);       // branchless prefetch
            kreg = *(const bf16x8*)&Kb[kgbase + (size_t)ktn * 2048];
            vreg = *(const bf16x8*)&Vt[vgbase + ktn * 32];
        }
        __syncthreads();

        // S = Q K^T + bias (two 16-key fragments)
        {
            const bf16x8 ka0 = *(const bf16x8*)&Ks[lm * 72 + quad * 8];
            const bf16x8 ka1 = *(const bf16x8*)&Ks[lm * 72 + 32 + quad * 8];
            s0 = __builtin_amdgcn_mfma_f32_16x16x32_bf16(qf0, ka0, s0, 0, 0, 0);
            s0 = __builtin_amdgcn_mfma_f32_16x16x32_bf16(qf1, ka1, s0, 0, 0, 0);
            const bf16x8 kb0 = *(const bf16x8*)&Ks[(16 + lm) * 72 + quad * 8];
            const bf16x8 kb1 = *(const bf16x8*)&Ks[(16 + lm) * 72 + 32 + quad * 8];
            s1 = __builtin_amdgcn_mfma_f32_16x16x32_bf16(qf0, kb0, s1, 0, 0, 0);
            s1 = __builtin_amdgcn_mfma_f32_16x16x32_bf16(qf1, kb1, s1, 0, 0, 0);
        }

        // p = exp2(fma(s, C2, -S2)); P packed bf16x2 at permuted positions
#pragma unroll
        for (int r = 0; r < 4; r++) {
            const float p0 = fast_exp2(fmaf(s0[r], C2, -S2));
            const float p1 = fast_exp2(fmaf(s1[r], C2, -S2));
            l_lane[r] += p0 + p1;
            bf16x2 pp; pp[0] = (bf16)p0; pp[1] = (bf16)p1;
            *(bf16x2*)&Pw[(quad * 4 + r) * 40 + lm * 2] = pp;
        }
        // advance keys by 32: 32 = 28 + 4
        wk0 += 4; hk0 += 1; if (wk0 >= 28) { wk0 -= 28; hk0 += 1; }
        wk1 += 4; hk1 += 1; if (wk1 >= 28) { wk1 -= 28; hk1 += 1; }

        __asm__ volatile("s_waitcnt lgkmcnt(0)" ::: "memory");
        const bf16x8 pf = *(const bf16x8*)&Pw[lm * 40 + quad * 8];
#pragma unroll
        for (int dt = 0; dt < 4; dt++) {
            const bf16x8 vf = *(const bf16x8*)&Vts[(dt * 16 + lm) * 40 + quad * 8];
            o[dt] = __builtin_amdgcn_mfma_f32_16x16x32_bf16(pf, vf, o[dt], 0, 0, 0);
        }
    }

    // single l reduction (16 lanes per row group), then epilogue
    const int qrow0 = q0 + qbase_l;
    if (q0 + wid * 16 < 1568) {
        const int bo = g >> 4, h = g & 15;
#pragma unroll
        for (int r = 0; r < 4; r++) {
            float ll = l_lane[r];
            for (int off = 1; off < 16; off <<= 1) ll += __shfl_xor(ll, off, 64);
            const float inv = 1.0f / ll;
            const size_t base = ((size_t)bo * 1568 + qrow0 + r) * 1024 + h * 64;
            for (int dt = 0; dt < 4; dt++)
                AO[base + dt * 16 + lm] = (bf16)(o[dt][r] * inv);
        }
    }
}

// ---------------------------------------------------------------------------
// Kernel 3a: output projection, both operands bf16 (W pre-converted).
__global__ __launch_bounds__(256) void proj_gemm_bf16(
    const bf16* __restrict__ A, const bf16* __restrict__ W,
    const float* __restrict__ bias, float* __restrict__ out) {
    __shared__ bf16 As[128 * 32];
    __shared__ bf16 Bs[128 * 32];
    const int t = threadIdx.x;
    const int wid = t >> 6, lane = t & 63;
    const int m0 = blockIdx.x * 128, n0 = blockIdx.y * 128;
    const int wm = (wid & 1) * 64, wn = (wid >> 1) * 64;
    const int r_i = lane >> 2, c8 = (lane & 3) * 8;
    const int lm = lane & 15, quad = lane >> 4;

    f32x4 acc[4][4] = {};
    for (int k0 = 0; k0 < 1024; k0 += 32) {
        __syncthreads();
        for (int i = 0; i < 2; i++) {
            const int blk = wid * 2 + i;
            async_cp16(A + (size_t)(m0 + blk * 16 + r_i) * 1024 + k0 + c8, As + blk * 512);
            async_cp16(W + (size_t)(n0 + blk * 16 + r_i) * 1024 + k0 + c8, Bs + blk * 512);
        }
        __syncthreads();
        bf16x8 af[4], bfr[4];
        for (int x = 0; x < 4; x++) {
            af[x]  = *(const bf16x8*)&As[(wm + x * 16 + lm) * 32 + quad * 8];
            bfr[x] = *(const bf16x8*)&Bs[(wn + x * 16 + lm) * 32 + quad * 8];
        }
        for (int mt = 0; mt < 4; mt++)
            for (int nt = 0; nt < 4; nt++)
                acc[mt][nt] = __builtin_amdgcn_mfma_f32_16x16x32_bf16(af[mt], bfr[nt], acc[mt][nt], 0, 0, 0);
    }
    for (int nt = 0; nt < 4; nt++) {
        const int n_ = n0 + wn + nt * 16 + lm;
        const float bv = bias[n_];
        for (int mt = 0; mt < 4; mt++)
            for (int r = 0; r < 4; r++) {
                const int m_ = m0 + wm + mt * 16 + quad * 4 + r;
                out[(size_t)m_ * 1024 + n_] = acc[mt][nt][r] + bv;
            }
    }
}

// Kernel 3b: fallback — W fp32, converted at stage time.
__global__ __launch_bounds__(256) void proj_gemm_f32(
    const bf16* __restrict__ A, const float* __restrict__ W,
    const float* __restrict__ bias, float* __restrict__ out) {
    __shared__ bf16 As[128 * 32];
    __shared__ bf16 Bs[128 * 32];
    const int t = threadIdx.x;
    const int wid = t >> 6, lane = t & 63;
    const int m0 = blockIdx.x * 128, n0 = blockIdx.y * 128;
    const int wm = (wid & 1) * 64, wn = (wid >> 1) * 64;
    const int r_i = lane >> 2, c8 = (lane & 3) * 8;
    const int lm = lane & 15, quad = lane >> 4;

    f32x4 acc[4][4] = {};
    for (int k0 = 0; k0 < 1024; k0 += 32) {
        __syncthreads();
        for (int i = 0; i < 2; i++) {
            const int blk = wid * 2 + i;
            async_cp16(A + (size_t)(m0 + blk * 16 + r_i) * 1024 + k0 + c8, As + blk * 512);
        }
        for (int i = 0; i < 4; i++) {
            const int idx = t + i * 256;
            const int row = idx >> 3, c4 = (idx & 7) * 4;
            const f32x4 wv = *(const f32x4*)&W[(size_t)(n0 + row) * 1024 + k0 + c4];
            *(bf16x4*)&Bs[row * 32 + c4] = cvt4(wv);
        }
        __syncthreads();
        bf16x8 af[4], bfr[4];
        for (int x = 0; x < 4; x++) {
            af[x]  = *(const bf16x8*)&As[(wm + x * 16 + lm) * 32 + quad * 8];
            bfr[x] = *(const bf16x8*)&Bs[(wn + x * 16 + lm) * 32 + quad * 8];
        }
        for (int mt = 0; mt < 4; mt++)
            for (int nt = 0; nt < 4; nt++)
                acc[mt][nt] = __builtin_amdgcn_mfma_f32_16x16x32_bf16(af[mt], bfr[nt], acc[mt][nt], 0, 0, 0);
    }
    for (int nt = 0; nt < 4; nt++) {
        const int n_ = n0 + wn + nt * 16 + lm;
        const float bv = bias[n_];
        for (int mt = 0; mt < 4; mt++)
            for (int r = 0; r < 4; r++) {
                const int m_ = m0 + wm + mt * 16 + quad * 4 + r;
                out[(size_t)m_ * 1024 + n_] = acc[mt][nt][r] + bv;
            }
    }
}

// ---------------------------------------------------------------------------
extern "C" void kernel_launch(void* const* d_in, const int* in_sizes, int n_in,
                              void* d_out, int out_size, void* d_ws, size_t ws_size,
                              hipStream_t stream) {
    const float* hs     = (const float*)d_in[0];
    const float* qkv_w  = (const float*)d_in[1];
    const float* qkv_b  = (const float*)d_in[2];
    const float* proj_w = (const float*)d_in[3];
    const float* proj_b = (const float*)d_in[4];
    const float* rph    = (const float*)d_in[5];
    const float* rpw    = (const float*)d_in[6];
    float* out = (float*)d_out;

    const size_t GQ = (size_t)64 * 1568 * 64;  // elems per Q/K/V
    const size_t N_HS = (size_t)6272 * 1024;
    const size_t N_QW = (size_t)3072 * 1024;
    const size_t N_PW = (size_t)1024 * 1024;
    bf16* Qb = (bf16*)d_ws;                    // [g][pix][64]
    bf16* Kb = Qb + GQ;                        // [g][pix][64]
    bf16* Vt = Kb + GQ;                        // [g][d][ppix] (permuted keys)
    bf16* AO = Vt + GQ;                        // [6272][1024]
    bf16* hs_bf    = AO + GQ;
    bf16* qkvw_bf  = hs_bf + N_HS;
    bf16* projw_bf = qkvw_bf + N_QW;
    const size_t need = (4 * GQ + N_HS + N_QW + N_PW) * sizeof(bf16); // 72.6 MB

    if (ws_size >= need) {
        cvt_kernel<<<512, 256, 0, stream>>>(hs, hs_bf, (int)(N_HS / 4));
        cvt_kernel<<<512, 256, 0, stream>>>(qkv_w, qkvw_bf, (int)(N_QW / 4));
        cvt_kernel<<<256, 256, 0, stream>>>(proj_w, projw_bf, (int)(N_PW / 4));
        qkv_gemm_bf16<<<dim3(49, 24), 256, 0, stream>>>(hs_bf, qkvw_bf, qkv_b, Qb, Kb, Vt);
        flash_attn<<<1600, 256, 0, stream>>>(Qb, Kb, Vt, rph, rpw, AO);
        proj_gemm_bf16<<<dim3(49, 8), 256, 0, stream>>>(AO, projw_bf, proj_b, out);
    } else {
        qkv_gemm_f32<<<dim3(49, 24), 256, 0, stream>>>(hs, qkv_w, qkv_b, Qb, Kb, Vt);
        flash_attn<<<1600, 256, 0, stream>>>(Qb, Kb, Vt, rph, rpw, AO);
        proj_gemm_f32<<<dim3(49, 8), 256, 0, stream>>>(AO, proj_w, proj_b, out);
    }
}